// Round 10
// baseline (152.331 us; speedup 1.0000x reference)
//
#include <hip/hip_runtime.h>
#include <cmath>

// CriticSNN forward: BATCH=65536, STATE_DIM=6, HIDDEN=128, NUM_STEPS=8, OUT=1
// One wave per batch element-QUAD; lane l owns neurons l and l+64 of each.
// Spikes are binary -> ballots; matmuls are masked column sums from LDS.
//
// v9: v7 (4-element interleave, all-LDS f32x4 table) with the register
// budget pinned via the backend attribute. Evidence across v5/v7/v8: the
// HIP __launch_bounds__ 2nd arg on this toolchain acts as min BLOCKS/CU
// (clamped to 32 waves/CU) and only ever TIGHTENS the VGPR budget
// (v5: 32 VGPR, v7/v8: 64 VGPR -> 80 MB scratch spill = the entire 85 us).
// amdgpu_waves_per_eu(4,4) states the true LDS-capped occupancy
// (1 block/CU = 16 waves/CU = 4 waves/SIMD) -> VGPR budget 512/4 = 128,
// which the ~100-register interleaved state needs.

typedef float f32x2 __attribute__((ext_vector_type(2)));
typedef float f32x4 __attribute__((ext_vector_type(4)));

constexpr int BATCH = 65536;
constexpr int HID   = 128;
constexpr int SDIM  = 6;
constexpr int NSTEP = 8;
constexpr int BLOCK = 1024;                         // 16 waves/block
constexpr int GRID  = 256;                          // 1 block per CU
constexpr int WAVES_TOTAL = GRID * (BLOCK / 64);    // 4096
constexpr int ELEMS_PER_WAVE = BATCH / WAVES_TOTAL; // 16
constexpr int NE = 4;                               // elements interleaved
constexpr int NQUAD = ELEMS_PER_WAVE / NE;          // 4 outer iterations

__global__ __launch_bounds__(BLOCK)
__attribute__((amdgpu_waves_per_eu(4, 4)))
void snn_fwd(
    const float* __restrict__ state,
    const float* __restrict__ w_fc1,
    const float* __restrict__ w_rec1,
    const float* __restrict__ w_fc2,
    const float* __restrict__ w_rec2,
    const float* __restrict__ w_mean,
    const float* __restrict__ w_std,
    const float* __restrict__ p_alpha1, const float* __restrict__ p_beta1,
    const float* __restrict__ p_thr1,
    const float* __restrict__ p_alpha2, const float* __restrict__ p_beta2,
    const float* __restrict__ p_thr2,
    float* __restrict__ out)
{
    // entry (j, l) at index j*64 + (l ^ (j & 63)); XOR swizzle keeps both the
    // staging writes and the uniform-j gather reads conflict-free.
    __shared__ f32x4 ldw[HID * 64];   // 128 KiB

    const int tid = threadIdx.x;

    for (int v = tid; v < HID * 64; v += BLOCK) {
        const int l = v >> 7;        // 0..63
        const int j = v & 127;       // consecutive lanes -> consecutive j
        const int pos = (j << 6) | (l ^ (j & 63));
        f32x4 w;
        w.x = w_rec1[l * HID + j];
        w.y = w_rec1[(l + 64) * HID + j];
        w.z = w_fc2 [l * HID + j];
        w.w = w_fc2 [(l + 64) * HID + j];
        ldw[pos] = w;
    }

    const int lane  = tid & 63;
    const int gwave = blockIdx.x * (BLOCK / 64) + (tid >> 6);

    // small weights -> registers
    f32x2 w1[SDIM];
    #pragma unroll
    for (int k = 0; k < SDIM; ++k) {
        w1[k].x = w_fc1[lane * SDIM + k];
        w1[k].y = w_fc1[(lane + 64) * SDIM + k];
    }
    const float wm_a = w_mean[lane], wm_b = w_mean[lane + 64];
    const float ws_a = w_std [lane], ws_b = w_std [lane + 64];

    const float a1 = fminf(fmaxf(p_alpha1[0], 0.f), 1.f);
    const float b1 = fminf(fmaxf(p_beta1 [0], 0.f), 1.f);
    const float a2 = fminf(fmaxf(p_alpha2[0], 0.f), 1.f);
    const float b2 = fminf(fmaxf(p_beta2 [0], 0.f), 1.f);
    const float t1 = p_thr1[0];
    const float t2 = p_thr2[0];
    const f32x2 a1v = {a1, a1}, b1v = {b1, b1}, a2v = {a2, a2}, b2v = {b2, b2};

    const float* __restrict__ rec2_a = w_rec2 + lane * HID;
    const float* __restrict__ rec2_b = w_rec2 + (lane + 64) * HID;

    __syncthreads();

    // fused gather over one spike mask: rec1 (next step) into r, fc2 (this
    // step) into f. One ds_read_b128 per set bit; hand-rotated.
    auto walk2 = [&](unsigned long long m, const f32x4* __restrict__ base,
                     f32x2& f, f32x2& r) {
        if (!m) return;
        int j = __builtin_ctzll(m); m &= m - 1;
        f32x4 w = base[(j << 6) | (lane ^ j)];
        while (m) {
            const int j2 = __builtin_ctzll(m); m &= m - 1;
            const f32x4 w2 = base[(j2 << 6) | (lane ^ j2)];
            r += __builtin_shufflevector(w, w, 0, 1);
            f += __builtin_shufflevector(w, w, 2, 3);
            w = w2;
        }
        r += __builtin_shufflevector(w, w, 0, 1);
        f += __builtin_shufflevector(w, w, 2, 3);
    };
    auto walkg = [&](unsigned long long m, int jbase, f32x2& f) {
        while (m) {
            const int j = __builtin_ctzll(m) + jbase; m &= m - 1;
            f.x += rec2_a[j];
            f.y += rec2_b[j];
        }
    };

    const f32x4* __restrict__ baseLo = ldw;
    const f32x4* __restrict__ baseHi = ldw + (64 << 6);

    for (int q = 0; q < NQUAD; ++q) {
        int bb[NE];
        #pragma unroll
        for (int i = 0; i < NE; ++i) bb[i] = gwave + WAVES_TOTAL * (q * NE + i);

        // cur1_in = state @ w_fc1.T (constant across steps)
        f32x2 cur[NE];
        #pragma unroll
        for (int i = 0; i < NE; ++i) {
            f32x2 c = {0.f, 0.f};
            #pragma unroll
            for (int k = 0; k < SDIM; ++k) {
                const float s = state[bb[i] * SDIM + k];   // wave-broadcast
                const f32x2 sv = {s, s};
                c = __builtin_elementwise_fma(sv, w1[k], c);
            }
            cur[i] = c;
        }

        f32x2 s1[NE], m1[NE], s2[NE], m2[NE], r[NE], cnt[NE];
        bool k1a[NE], k1b[NE], k2a[NE], k2b[NE];
        unsigned long long M2a[NE], M2b[NE];
        #pragma unroll
        for (int i = 0; i < NE; ++i) {
            s1[i] = (f32x2){0.f, 0.f}; m1[i] = (f32x2){0.f, 0.f};
            s2[i] = (f32x2){0.f, 0.f}; m2[i] = (f32x2){0.f, 0.f};
            r [i] = (f32x2){0.f, 0.f}; cnt[i] = (f32x2){0.f, 0.f};
            k1a[i] = k1b[i] = k2a[i] = k2b[i] = false;
            M2a[i] = 0ull; M2b[i] = 0ull;
        }

        #pragma unroll 1
        for (int t = 0; t < NSTEP; ++t) {
            // ----- layer 1 (all elements) -----
            unsigned long long M1a[NE], M1b[NE];
            #pragma unroll
            for (int i = 0; i < NE; ++i) {
                s1[i] = __builtin_elementwise_fma(a1v, s1[i], cur[i] + r[i]);
                const f32x2 rst1 = {k1a[i] ? t1 : 0.f, k1b[i] ? t1 : 0.f};
                m1[i] = __builtin_elementwise_fma(b1v, m1[i], s1[i]) - rst1;
                k1a[i] = (m1[i].x - t1) > 0.f;
                k1b[i] = (m1[i].y - t1) > 0.f;
                M1a[i] = __ballot(k1a[i]);
                M1b[i] = __ballot(k1b[i]);
            }

            // ----- fused gathers: fc2 (this step) + rec1 (next step) -----
            // 8 independent walks -> loads from different elements overlap.
            f32x2 f[NE];
            #pragma unroll
            for (int i = 0; i < NE; ++i) {
                f[i] = (f32x2){0.f, 0.f};
                r[i] = (f32x2){0.f, 0.f};
            }
            #pragma unroll
            for (int i = 0; i < NE; ++i) walk2(M1a[i], baseLo, f[i], r[i]);
            #pragma unroll
            for (int i = 0; i < NE; ++i) walk2(M1b[i], baseHi, f[i], r[i]);

            // rare layer-2 recurrence
            unsigned long long anyM2 = 0ull;
            #pragma unroll
            for (int i = 0; i < NE; ++i) anyM2 |= M2a[i] | M2b[i];
            if (anyM2 != 0ull) {
                #pragma unroll
                for (int i = 0; i < NE; ++i) {
                    walkg(M2a[i], 0,  f[i]);
                    walkg(M2b[i], 64, f[i]);
                }
            }

            // ----- layer 2 (all elements) -----
            #pragma unroll
            for (int i = 0; i < NE; ++i) {
                s2[i] = __builtin_elementwise_fma(a2v, s2[i], f[i]);
                const f32x2 rst2 = {k2a[i] ? t2 : 0.f, k2b[i] ? t2 : 0.f};
                m2[i] = __builtin_elementwise_fma(b2v, m2[i], s2[i]) - rst2;
                k2a[i] = (m2[i].x - t2) > 0.f;
                k2b[i] = (m2[i].y - t2) > 0.f;
                M2a[i] = __ballot(k2a[i]);
                M2b[i] = __ballot(k2b[i]);
                const f32x2 one = {k2a[i] ? 1.f : 0.f, k2b[i] ? 1.f : 0.f};
                cnt[i] += one;
            }
        }

        // ----- head: dot(avg_spikes, w_mean/w_std) + activations -----
        #pragma unroll
        for (int i = 0; i < NE; ++i) {
            const float av_a = cnt[i].x * (1.f / (float)NSTEP);
            const float av_b = cnt[i].y * (1.f / (float)NSTEP);
            float dm = av_a * wm_a + av_b * wm_b;
            float ds = av_a * ws_a + av_b * ws_b;
            #pragma unroll
            for (int off = 32; off > 0; off >>= 1) {
                dm += __shfl_xor(dm, off, 64);
                ds += __shfl_xor(ds, off, 64);
            }
            if (lane == 0) {
                out[bb[i]] = tanhf(dm);
                const float sg = 1.f / (1.f + expf(-(ds + 2.f)));
                out[BATCH + bb[i]] = 1.9f * sg + 0.1f;
            }
        }
    }
}

extern "C" void kernel_launch(void* const* d_in, const int* in_sizes, int n_in,
                              void* d_out, int out_size, void* d_ws, size_t ws_size,
                              hipStream_t stream) {
    (void)in_sizes; (void)n_in; (void)d_ws; (void)ws_size; (void)out_size;
    snn_fwd<<<GRID, BLOCK, 0, stream>>>(
        (const float*)d_in[0],  // state
        (const float*)d_in[1],  // w_fc1
        (const float*)d_in[2],  // w_rec1
        (const float*)d_in[3],  // w_fc2
        (const float*)d_in[4],  // w_rec2
        (const float*)d_in[5],  // w_mean
        (const float*)d_in[6],  // w_std
        (const float*)d_in[7],  // alpha1
        (const float*)d_in[8],  // beta1
        (const float*)d_in[9],  // thr1
        (const float*)d_in[10], // alpha2
        (const float*)d_in[11], // beta2
        (const float*)d_in[12], // thr2
        (float*)d_out);
}

// Round 11
// 128.587 us; speedup vs baseline: 1.1847x; 1.1847x over previous
//
#include <hip/hip_runtime.h>
#include <cmath>

// CriticSNN forward: BATCH=65536, STATE_DIM=6, HIDDEN=128, NUM_STEPS=8, OUT=1
// One wave per batch element-PAIR; lane l owns neurons l and l+64 of each.
// Spikes are binary -> ballots; matmuls are masked column sums from LDS.
//
// v10: latency surgery on the bit-walk. Evidence: v4's 52us ~= 8 pairs x
// 8 steps x 4 walks x ~4 bits x ~120cy LDS latency -- the rotated walk keeps
// only ONE ds_read outstanding (in-order issue), so every set bit pays full
// LDS latency. Fix: batch 4 bits per iteration -- issue 4 independent
// ds_read_b128 back-to-back, then accumulate; latency amortizes 4x.
// Constraint learned from v5/v7/v8/v9: the toolchain pins VGPR to <=64 for
// 1024-thread blocks (no attribute overrides it), so NE stays 2 and the
// +16 transient load regs are paid for by dropping the state prefetch and
// scoping the fc1 weights to the quad prologue.

typedef float f32x2 __attribute__((ext_vector_type(2)));
typedef float f32x4 __attribute__((ext_vector_type(4)));

constexpr int BATCH = 65536;
constexpr int HID   = 128;
constexpr int SDIM  = 6;
constexpr int NSTEP = 8;
constexpr int BLOCK = 1024;                         // 16 waves/block
constexpr int GRID  = 256;                          // 1 block per CU
constexpr int WAVES_TOTAL = GRID * (BLOCK / 64);    // 4096
constexpr int ELEMS_PER_WAVE = BATCH / WAVES_TOTAL; // 16
constexpr int PAIRS = ELEMS_PER_WAVE / 2;           // 8

__global__ __launch_bounds__(BLOCK) void snn_fwd(
    const float* __restrict__ state,
    const float* __restrict__ w_fc1,
    const float* __restrict__ w_rec1,
    const float* __restrict__ w_fc2,
    const float* __restrict__ w_rec2,
    const float* __restrict__ w_mean,
    const float* __restrict__ w_std,
    const float* __restrict__ p_alpha1, const float* __restrict__ p_beta1,
    const float* __restrict__ p_thr1,
    const float* __restrict__ p_alpha2, const float* __restrict__ p_beta2,
    const float* __restrict__ p_thr2,
    float* __restrict__ out)
{
    // entry (j, l) at index j*64 + (l ^ (j & 63)); XOR swizzle keeps both the
    // staging writes and the uniform-j gather reads conflict-free.
    __shared__ f32x4 ldw[HID * 64];   // 128 KiB

    const int tid = threadIdx.x;

    for (int v = tid; v < HID * 64; v += BLOCK) {
        const int l = v >> 7;        // 0..63
        const int j = v & 127;       // consecutive lanes -> consecutive j
        const int pos = (j << 6) | (l ^ (j & 63));
        f32x4 w;
        w.x = w_rec1[l * HID + j];
        w.y = w_rec1[(l + 64) * HID + j];
        w.z = w_fc2 [l * HID + j];
        w.w = w_fc2 [(l + 64) * HID + j];
        ldw[pos] = w;
    }

    const int lane  = tid & 63;
    const int gwave = blockIdx.x * (BLOCK / 64) + (tid >> 6);

    const float wm_a = w_mean[lane], wm_b = w_mean[lane + 64];
    const float ws_a = w_std [lane], ws_b = w_std [lane + 64];

    const float a1 = fminf(fmaxf(p_alpha1[0], 0.f), 1.f);
    const float b1 = fminf(fmaxf(p_beta1 [0], 0.f), 1.f);
    const float a2 = fminf(fmaxf(p_alpha2[0], 0.f), 1.f);
    const float b2 = fminf(fmaxf(p_beta2 [0], 0.f), 1.f);
    const float t1 = p_thr1[0];
    const float t2 = p_thr2[0];
    const f32x2 a1v = {a1, a1}, b1v = {b1, b1}, a2v = {a2, a2}, b2v = {b2, b2};

    const float* __restrict__ rec2_a = w_rec2 + lane * HID;
    const float* __restrict__ rec2_b = w_rec2 + (lane + 64) * HID;

    __syncthreads();

    // batched gather over one spike mask: rec1 (next step) into r, fc2 (this
    // step) into f. Up to 4 independent ds_read_b128 in flight per batch.
    auto walk2 = [&](unsigned long long m, const f32x4* __restrict__ base,
                     f32x2& f, f32x2& r) {
        while (__builtin_popcountll(m) >= 4) {
            int j0 = __builtin_ctzll(m); m &= m - 1;
            int j1 = __builtin_ctzll(m); m &= m - 1;
            int j2 = __builtin_ctzll(m); m &= m - 1;
            int j3 = __builtin_ctzll(m); m &= m - 1;
            const f32x4 w0 = base[(j0 << 6) | (lane ^ j0)];
            const f32x4 w1 = base[(j1 << 6) | (lane ^ j1)];
            const f32x4 w2 = base[(j2 << 6) | (lane ^ j2)];
            const f32x4 w3 = base[(j3 << 6) | (lane ^ j3)];
            r += __builtin_shufflevector(w0, w0, 0, 1);
            f += __builtin_shufflevector(w0, w0, 2, 3);
            r += __builtin_shufflevector(w1, w1, 0, 1);
            f += __builtin_shufflevector(w1, w1, 2, 3);
            r += __builtin_shufflevector(w2, w2, 0, 1);
            f += __builtin_shufflevector(w2, w2, 2, 3);
            r += __builtin_shufflevector(w3, w3, 0, 1);
            f += __builtin_shufflevector(w3, w3, 2, 3);
        }
        if (m) {
            const int nrem = __builtin_popcountll(m);
            f32x4 w0, w1, w2;
            { const int j = __builtin_ctzll(m); m &= m - 1;
              w0 = base[(j << 6) | (lane ^ j)]; }
            if (nrem > 1) { const int j = __builtin_ctzll(m); m &= m - 1;
                            w1 = base[(j << 6) | (lane ^ j)]; }
            if (nrem > 2) { const int j = __builtin_ctzll(m); m &= m - 1;
                            w2 = base[(j << 6) | (lane ^ j)]; }
            r += __builtin_shufflevector(w0, w0, 0, 1);
            f += __builtin_shufflevector(w0, w0, 2, 3);
            if (nrem > 1) {
                r += __builtin_shufflevector(w1, w1, 0, 1);
                f += __builtin_shufflevector(w1, w1, 2, 3);
            }
            if (nrem > 2) {
                r += __builtin_shufflevector(w2, w2, 0, 1);
                f += __builtin_shufflevector(w2, w2, 2, 3);
            }
        }
    };
    // layer-2 recurrence is almost never active: straight global reads
    auto walkg = [&](unsigned long long m, int jbase, f32x2& f) {
        while (m) {
            const int j = __builtin_ctzll(m) + jbase; m &= m - 1;
            f.x += rec2_a[j];
            f.y += rec2_b[j];
        }
    };

    const f32x4* __restrict__ baseLo = ldw;
    const f32x4* __restrict__ baseHi = ldw + (64 << 6);

    for (int e = 0; e < PAIRS; ++e) {
        const int bx = gwave + WAVES_TOTAL * (2 * e);
        const int by = gwave + WAVES_TOTAL * (2 * e + 1);

        // cur1_in = state @ w_fc1.T (constant across steps; fc1 weights are
        // scoped here so their registers die before the step loop)
        f32x2 curx = {0.f, 0.f}, cury = {0.f, 0.f};
        {
            #pragma unroll
            for (int k = 0; k < SDIM; ++k) {
                f32x2 w1k;
                w1k.x = w_fc1[lane * SDIM + k];
                w1k.y = w_fc1[(lane + 64) * SDIM + k];
                const float sx = state[bx * SDIM + k];   // wave-broadcast
                const float sy = state[by * SDIM + k];
                const f32x2 sxv = {sx, sx};
                const f32x2 syv = {sy, sy};
                curx = __builtin_elementwise_fma(sxv, w1k, curx);
                cury = __builtin_elementwise_fma(syv, w1k, cury);
            }
        }

        f32x2 s1x = {0.f, 0.f}, m1x = {0.f, 0.f}, s2x = {0.f, 0.f}, m2x = {0.f, 0.f};
        f32x2 s1y = {0.f, 0.f}, m1y = {0.f, 0.f}, s2y = {0.f, 0.f}, m2y = {0.f, 0.f};
        bool k1xa = false, k1xb = false, k2xa = false, k2xb = false;
        bool k1ya = false, k1yb = false, k2ya = false, k2yb = false;
        f32x2 cx = {0.f, 0.f}, cy = {0.f, 0.f};
        unsigned long long M2xa = 0ull, M2xb = 0ull, M2ya = 0ull, M2yb = 0ull;
        f32x2 rx = {0.f, 0.f}, ry = {0.f, 0.f};   // rec1 contribution

        #pragma unroll 1
        for (int t = 0; t < NSTEP; ++t) {
            // ----- layer 1 (both elements; r* computed last step) -----
            s1x = __builtin_elementwise_fma(a1v, s1x, curx + rx);
            s1y = __builtin_elementwise_fma(a1v, s1y, cury + ry);
            const f32x2 rst1x = {k1xa ? t1 : 0.f, k1xb ? t1 : 0.f};
            const f32x2 rst1y = {k1ya ? t1 : 0.f, k1yb ? t1 : 0.f};
            m1x = __builtin_elementwise_fma(b1v, m1x, s1x) - rst1x;
            m1y = __builtin_elementwise_fma(b1v, m1y, s1y) - rst1y;
            k1xa = (m1x.x - t1) > 0.f;
            k1xb = (m1x.y - t1) > 0.f;
            k1ya = (m1y.x - t1) > 0.f;
            k1yb = (m1y.y - t1) > 0.f;
            const unsigned long long M1xa = __ballot(k1xa);
            const unsigned long long M1xb = __ballot(k1xb);
            const unsigned long long M1ya = __ballot(k1ya);
            const unsigned long long M1yb = __ballot(k1yb);

            // ----- fused batched gathers: fc2 (this step) + rec1 (next) ---
            f32x2 fx = {0.f, 0.f}, fy = {0.f, 0.f};
            rx = (f32x2){0.f, 0.f}; ry = (f32x2){0.f, 0.f};
            walk2(M1xa, baseLo, fx, rx);
            walk2(M1xb, baseHi, fx, rx);
            walk2(M1ya, baseLo, fy, ry);
            walk2(M1yb, baseHi, fy, ry);

            // rare layer-2 recurrence
            if ((M2xa | M2xb | M2ya | M2yb) != 0ull) {
                walkg(M2xa, 0,  fx);
                walkg(M2xb, 64, fx);
                walkg(M2ya, 0,  fy);
                walkg(M2yb, 64, fy);
            }

            // ----- layer 2 (both elements) -----
            s2x = __builtin_elementwise_fma(a2v, s2x, fx);
            s2y = __builtin_elementwise_fma(a2v, s2y, fy);
            const f32x2 rst2x = {k2xa ? t2 : 0.f, k2xb ? t2 : 0.f};
            const f32x2 rst2y = {k2ya ? t2 : 0.f, k2yb ? t2 : 0.f};
            m2x = __builtin_elementwise_fma(b2v, m2x, s2x) - rst2x;
            m2y = __builtin_elementwise_fma(b2v, m2y, s2y) - rst2y;
            k2xa = (m2x.x - t2) > 0.f;
            k2xb = (m2x.y - t2) > 0.f;
            k2ya = (m2y.x - t2) > 0.f;
            k2yb = (m2y.y - t2) > 0.f;
            M2xa = __ballot(k2xa);
            M2xb = __ballot(k2xb);
            M2ya = __ballot(k2ya);
            M2yb = __ballot(k2yb);
            const f32x2 onex = {k2xa ? 1.f : 0.f, k2xb ? 1.f : 0.f};
            const f32x2 oney = {k2ya ? 1.f : 0.f, k2yb ? 1.f : 0.f};
            cx += onex;
            cy += oney;
        }

        // ----- head: dot(avg_spikes, w_mean/w_std) + activations -----
        const float axa = cx.x * (1.f / (float)NSTEP);
        const float axb = cx.y * (1.f / (float)NSTEP);
        const float aya = cy.x * (1.f / (float)NSTEP);
        const float ayb = cy.y * (1.f / (float)NSTEP);
        float dmx = axa * wm_a + axb * wm_b;
        float dsx = axa * ws_a + axb * ws_b;
        float dmy = aya * wm_a + ayb * wm_b;
        float dsy = aya * ws_a + ayb * ws_b;
        #pragma unroll
        for (int off = 32; off > 0; off >>= 1) {
            dmx += __shfl_xor(dmx, off, 64);
            dsx += __shfl_xor(dsx, off, 64);
            dmy += __shfl_xor(dmy, off, 64);
            dsy += __shfl_xor(dsy, off, 64);
        }
        if (lane == 0) {
            out[bx] = tanhf(dmx);
            out[by] = tanhf(dmy);
            const float sgx = 1.f / (1.f + expf(-(dsx + 2.f)));
            const float sgy = 1.f / (1.f + expf(-(dsy + 2.f)));
            out[BATCH + bx] = 1.9f * sgx + 0.1f;
            out[BATCH + by] = 1.9f * sgy + 0.1f;
        }
    }
}

extern "C" void kernel_launch(void* const* d_in, const int* in_sizes, int n_in,
                              void* d_out, int out_size, void* d_ws, size_t ws_size,
                              hipStream_t stream) {
    (void)in_sizes; (void)n_in; (void)d_ws; (void)ws_size; (void)out_size;
    snn_fwd<<<GRID, BLOCK, 0, stream>>>(
        (const float*)d_in[0],  // state
        (const float*)d_in[1],  // w_fc1
        (const float*)d_in[2],  // w_rec1
        (const float*)d_in[3],  // w_fc2
        (const float*)d_in[4],  // w_rec2
        (const float*)d_in[5],  // w_mean
        (const float*)d_in[6],  // w_std
        (const float*)d_in[7],  // alpha1
        (const float*)d_in[8],  // beta1
        (const float*)d_in[9],  // thr1
        (const float*)d_in[10], // alpha2
        (const float*)d_in[11], // beta2
        (const float*)d_in[12], // thr2
        (float*)d_out);
}

// Round 12
// 123.169 us; speedup vs baseline: 1.2368x; 1.0440x over previous
//
#include <hip/hip_runtime.h>
#include <cmath>

// CriticSNN forward: BATCH=65536, STATE_DIM=6, HIDDEN=128, NUM_STEPS=8, OUT=1
// One wave per batch element-PAIR; lane l owns neurons l and l+64 of each.
// Spikes are binary -> ballots; matmuls are masked column sums from LDS.
//
// v11: revert to v4's proven structure (52us champion; v10's 4-bit batching
// regressed to 58.7 because masks hold 0-3 bits and the remainder path is
// pure overhead). Deltas vs v4:
//  - v4 walk order (xa,ya,xb,yb: consecutive walks from different elements)
//    PLUS private per-walk f32x4 accumulators -> all 4 walks' chains fully
//    independent, merged after.
//  - wave-uniform early-out when no spikes anywhere (early steps are
//    spike-free: skips the whole gather phase ~25-40% of step-iters).
//  - no state prefetch (v10 showed it's free to drop; scalar loads hide
//    under walks), freeing regs for the accumulators. VGPR must stay <=64
//    (toolchain pins 1024-thread blocks there; v5/v7/v8/v9 evidence).

typedef float f32x2 __attribute__((ext_vector_type(2)));
typedef float f32x4 __attribute__((ext_vector_type(4)));

constexpr int BATCH = 65536;
constexpr int HID   = 128;
constexpr int SDIM  = 6;
constexpr int NSTEP = 8;
constexpr int BLOCK = 1024;                         // 16 waves/block
constexpr int GRID  = 256;                          // 1 block per CU
constexpr int WAVES_TOTAL = GRID * (BLOCK / 64);    // 4096
constexpr int ELEMS_PER_WAVE = BATCH / WAVES_TOTAL; // 16
constexpr int PAIRS = ELEMS_PER_WAVE / 2;           // 8

__global__ __launch_bounds__(BLOCK) void snn_fwd(
    const float* __restrict__ state,
    const float* __restrict__ w_fc1,
    const float* __restrict__ w_rec1,
    const float* __restrict__ w_fc2,
    const float* __restrict__ w_rec2,
    const float* __restrict__ w_mean,
    const float* __restrict__ w_std,
    const float* __restrict__ p_alpha1, const float* __restrict__ p_beta1,
    const float* __restrict__ p_thr1,
    const float* __restrict__ p_alpha2, const float* __restrict__ p_beta2,
    const float* __restrict__ p_thr2,
    float* __restrict__ out)
{
    // entry (j, l) at index j*64 + (l ^ (j & 63)); XOR swizzle keeps both the
    // staging writes and the uniform-j gather reads conflict-free.
    __shared__ f32x4 ldw[HID * 64];   // 128 KiB

    const int tid = threadIdx.x;

    for (int v = tid; v < HID * 64; v += BLOCK) {
        const int l = v >> 7;        // 0..63
        const int j = v & 127;       // consecutive lanes -> consecutive j
        const int pos = (j << 6) | (l ^ (j & 63));
        f32x4 w;
        w.x = w_rec1[l * HID + j];
        w.y = w_rec1[(l + 64) * HID + j];
        w.z = w_fc2 [l * HID + j];
        w.w = w_fc2 [(l + 64) * HID + j];
        ldw[pos] = w;
    }

    const int lane  = tid & 63;
    const int gwave = blockIdx.x * (BLOCK / 64) + (tid >> 6);

    const float wm_a = w_mean[lane], wm_b = w_mean[lane + 64];
    const float ws_a = w_std [lane], ws_b = w_std [lane + 64];

    const float a1 = fminf(fmaxf(p_alpha1[0], 0.f), 1.f);
    const float b1 = fminf(fmaxf(p_beta1 [0], 0.f), 1.f);
    const float a2 = fminf(fmaxf(p_alpha2[0], 0.f), 1.f);
    const float b2 = fminf(fmaxf(p_beta2 [0], 0.f), 1.f);
    const float t1 = p_thr1[0];
    const float t2 = p_thr2[0];
    const f32x2 a1v = {a1, a1}, b1v = {b1, b1}, a2v = {a2, a2}, b2v = {b2, b2};

    const float* __restrict__ rec2_a = w_rec2 + lane * HID;
    const float* __restrict__ rec2_b = w_rec2 + (lane + 64) * HID;

    __syncthreads();

    // rotated walk over one spike mask with a PRIVATE f32x4 accumulator:
    // acc.xy = rec1 (next step), acc.zw = fc2 (this step).
    auto walk = [&](unsigned long long m, const f32x4* __restrict__ base) -> f32x4 {
        f32x4 acc = {0.f, 0.f, 0.f, 0.f};
        if (!m) return acc;
        int j = __builtin_ctzll(m); m &= m - 1;
        f32x4 w = base[(j << 6) | (lane ^ j)];
        while (m) {
            const int j2 = __builtin_ctzll(m); m &= m - 1;
            const f32x4 w2 = base[(j2 << 6) | (lane ^ j2)];
            acc += w;
            w = w2;
        }
        acc += w;
        return acc;
    };
    // layer-2 recurrence is almost never active: straight global reads
    auto walkg = [&](unsigned long long m, int jbase, f32x2& f) {
        while (m) {
            const int j = __builtin_ctzll(m) + jbase; m &= m - 1;
            f.x += rec2_a[j];
            f.y += rec2_b[j];
        }
    };

    const f32x4* __restrict__ baseLo = ldw;
    const f32x4* __restrict__ baseHi = ldw + (64 << 6);

    for (int e = 0; e < PAIRS; ++e) {
        const int bx = gwave + WAVES_TOTAL * (2 * e);
        const int by = gwave + WAVES_TOTAL * (2 * e + 1);

        // cur1_in = state @ w_fc1.T (constant across steps; fc1 weights
        // scoped here so their registers die before the step loop)
        f32x2 curx = {0.f, 0.f}, cury = {0.f, 0.f};
        {
            #pragma unroll
            for (int k = 0; k < SDIM; ++k) {
                f32x2 w1k;
                w1k.x = w_fc1[lane * SDIM + k];
                w1k.y = w_fc1[(lane + 64) * SDIM + k];
                const float sx = state[bx * SDIM + k];   // wave-broadcast
                const float sy = state[by * SDIM + k];
                const f32x2 sxv = {sx, sx};
                const f32x2 syv = {sy, sy};
                curx = __builtin_elementwise_fma(sxv, w1k, curx);
                cury = __builtin_elementwise_fma(syv, w1k, cury);
            }
        }

        f32x2 s1x = {0.f, 0.f}, m1x = {0.f, 0.f}, s2x = {0.f, 0.f}, m2x = {0.f, 0.f};
        f32x2 s1y = {0.f, 0.f}, m1y = {0.f, 0.f}, s2y = {0.f, 0.f}, m2y = {0.f, 0.f};
        bool k1xa = false, k1xb = false, k2xa = false, k2xb = false;
        bool k1ya = false, k1yb = false, k2ya = false, k2yb = false;
        f32x2 cx = {0.f, 0.f}, cy = {0.f, 0.f};
        unsigned long long M2xa = 0ull, M2xb = 0ull, M2ya = 0ull, M2yb = 0ull;
        f32x2 rx = {0.f, 0.f}, ry = {0.f, 0.f};   // rec1 contribution

        #pragma unroll 1
        for (int t = 0; t < NSTEP; ++t) {
            // ----- layer 1 (both elements; r* computed last step) -----
            s1x = __builtin_elementwise_fma(a1v, s1x, curx + rx);
            s1y = __builtin_elementwise_fma(a1v, s1y, cury + ry);
            const f32x2 rst1x = {k1xa ? t1 : 0.f, k1xb ? t1 : 0.f};
            const f32x2 rst1y = {k1ya ? t1 : 0.f, k1yb ? t1 : 0.f};
            m1x = __builtin_elementwise_fma(b1v, m1x, s1x) - rst1x;
            m1y = __builtin_elementwise_fma(b1v, m1y, s1y) - rst1y;
            k1xa = (m1x.x - t1) > 0.f;
            k1xb = (m1x.y - t1) > 0.f;
            k1ya = (m1y.x - t1) > 0.f;
            k1yb = (m1y.y - t1) > 0.f;
            const unsigned long long M1xa = __ballot(k1xa);
            const unsigned long long M1xb = __ballot(k1xb);
            const unsigned long long M1ya = __ballot(k1ya);
            const unsigned long long M1yb = __ballot(k1yb);

            f32x2 fx = {0.f, 0.f}, fy = {0.f, 0.f};
            rx = (f32x2){0.f, 0.f}; ry = (f32x2){0.f, 0.f};

            // wave-uniform early-out: spike-free steps skip the whole
            // gather phase (common in the first few steps).
            if ((M1xa | M1xb | M1ya | M1yb | M2xa | M2xb | M2ya | M2yb) != 0ull) {
                // 4 independent walks (alternating elements), private accs
                const f32x4 axLo = walk(M1xa, baseLo);
                const f32x4 ayLo = walk(M1ya, baseLo);
                const f32x4 axHi = walk(M1xb, baseHi);
                const f32x4 ayHi = walk(M1yb, baseHi);
                const f32x4 ax = axLo + axHi;
                const f32x4 ay = ayLo + ayHi;
                rx = __builtin_shufflevector(ax, ax, 0, 1);
                fx = __builtin_shufflevector(ax, ax, 2, 3);
                ry = __builtin_shufflevector(ay, ay, 0, 1);
                fy = __builtin_shufflevector(ay, ay, 2, 3);

                // rare layer-2 recurrence
                if ((M2xa | M2xb | M2ya | M2yb) != 0ull) {
                    walkg(M2xa, 0,  fx);
                    walkg(M2xb, 64, fx);
                    walkg(M2ya, 0,  fy);
                    walkg(M2yb, 64, fy);
                }
            }

            // ----- layer 2 (both elements) -----
            s2x = __builtin_elementwise_fma(a2v, s2x, fx);
            s2y = __builtin_elementwise_fma(a2v, s2y, fy);
            const f32x2 rst2x = {k2xa ? t2 : 0.f, k2xb ? t2 : 0.f};
            const f32x2 rst2y = {k2ya ? t2 : 0.f, k2yb ? t2 : 0.f};
            m2x = __builtin_elementwise_fma(b2v, m2x, s2x) - rst2x;
            m2y = __builtin_elementwise_fma(b2v, m2y, s2y) - rst2y;
            k2xa = (m2x.x - t2) > 0.f;
            k2xb = (m2x.y - t2) > 0.f;
            k2ya = (m2y.x - t2) > 0.f;
            k2yb = (m2y.y - t2) > 0.f;
            M2xa = __ballot(k2xa);
            M2xb = __ballot(k2xb);
            M2ya = __ballot(k2ya);
            M2yb = __ballot(k2yb);
            const f32x2 onex = {k2xa ? 1.f : 0.f, k2xb ? 1.f : 0.f};
            const f32x2 oney = {k2ya ? 1.f : 0.f, k2yb ? 1.f : 0.f};
            cx += onex;
            cy += oney;
        }

        // ----- head: dot(avg_spikes, w_mean/w_std) + activations -----
        const float axa = cx.x * (1.f / (float)NSTEP);
        const float axb = cx.y * (1.f / (float)NSTEP);
        const float aya = cy.x * (1.f / (float)NSTEP);
        const float ayb = cy.y * (1.f / (float)NSTEP);
        float dmx = axa * wm_a + axb * wm_b;
        float dsx = axa * ws_a + axb * ws_b;
        float dmy = aya * wm_a + ayb * wm_b;
        float dsy = aya * ws_a + ayb * ws_b;
        #pragma unroll
        for (int off = 32; off > 0; off >>= 1) {
            dmx += __shfl_xor(dmx, off, 64);
            dsx += __shfl_xor(dsx, off, 64);
            dmy += __shfl_xor(dmy, off, 64);
            dsy += __shfl_xor(dsy, off, 64);
        }
        if (lane == 0) {
            out[bx] = tanhf(dmx);
            out[by] = tanhf(dmy);
            const float sgx = 1.f / (1.f + expf(-(dsx + 2.f)));
            const float sgy = 1.f / (1.f + expf(-(dsy + 2.f)));
            out[BATCH + bx] = 1.9f * sgx + 0.1f;
            out[BATCH + by] = 1.9f * sgy + 0.1f;
        }
    }
}

extern "C" void kernel_launch(void* const* d_in, const int* in_sizes, int n_in,
                              void* d_out, int out_size, void* d_ws, size_t ws_size,
                              hipStream_t stream) {
    (void)in_sizes; (void)n_in; (void)d_ws; (void)ws_size; (void)out_size;
    snn_fwd<<<GRID, BLOCK, 0, stream>>>(
        (const float*)d_in[0],  // state
        (const float*)d_in[1],  // w_fc1
        (const float*)d_in[2],  // w_rec1
        (const float*)d_in[3],  // w_fc2
        (const float*)d_in[4],  // w_rec2
        (const float*)d_in[5],  // w_mean
        (const float*)d_in[6],  // w_std
        (const float*)d_in[7],  // alpha1
        (const float*)d_in[8],  // beta1
        (const float*)d_in[9],  // thr1
        (const float*)d_in[10], // alpha2
        (const float*)d_in[11], // beta2
        (const float*)d_in[12], // thr2
        (float*)d_out);
}